// Round 10
// baseline (387.399 us; speedup 1.0000x reference)
//
#include <hip/hip_runtime.h>
#include <stdint.h>

#define B_ 4
#define N_ 2048
#define C_ 1024
#define H_ 16
#define D_ 64
#define M_ (B_*N_)      // 8192 rows
#define N3_ (3*C_)      // 3072

typedef __attribute__((ext_vector_type(8))) __bf16 bf16x8;
typedef bf16x8 bf16x8_ma __attribute__((may_alias));
typedef __attribute__((ext_vector_type(4))) float floatx4;
typedef unsigned short u16;
typedef unsigned int u32;

typedef __attribute__((address_space(1))) const void void_g;
typedef __attribute__((address_space(3))) void void_l;

__device__ __forceinline__ void glds16(const void* g, void* l) {
  __builtin_amdgcn_global_load_lds((void_g*)g, (void_l*)l, 16, 0, 0);
}

__device__ __forceinline__ u16 f2bf(float f) {
  union { float f; u32 u; } x; x.f = f;
  u32 r = x.u + 0x7fffu + ((x.u >> 16) & 1u);   // RNE
  return (u16)(r >> 16);
}

__device__ __forceinline__ float fexp2(float x) {
#if __has_builtin(__builtin_amdgcn_exp2f)
  return __builtin_amdgcn_exp2f(x);
#else
  return exp2f(x);
#endif
}

// T1 swizzle: kept ONLY for flash (R6 isolated: helps flash KV locality,
// null-to-harmful FETCH on the gemm).
__device__ __forceinline__ int xcd_swz(int hw, int nwg) {
  int per = nwg >> 3;
  return (hw & 7) * per + (hw >> 3);
}

// ---------------- fused prep: x->bf16 + both weight transposes -----------
// R10: 3 dispatches -> 1 (saves 2 launch gaps). Block-uniform branch by
// blockIdx range; barrier only inside the transpose branches (uniform).
__global__ __launch_bounds__(256)
void prep(const float4* __restrict__ x4, uint2* __restrict__ xb,
          const float* __restrict__ Wqkv, u16* __restrict__ Wt_qkv,
          const float* __restrict__ Wproj, u16* __restrict__ Wt_proj) {
  __shared__ u16 tile[64][65];
  int id = blockIdx.x;
  int tid = threadIdx.x;

  if (id < 8192) {                       // convert_x: 8192*256 == M_*C_/4
    int idx = id * 256 + tid;
    float4 v = x4[idx];
    union { u16 a[4]; uint2 u; } p;
    p.a[0] = f2bf(v.x); p.a[1] = f2bf(v.y); p.a[2] = f2bf(v.z); p.a[3] = f2bf(v.w);
    xb[idx] = p.u;
    return;
  }

  const float* in; u16* out; int R, Ccols, c0, r0;
  if (id < 8192 + 768) {                 // Wqkv transpose: 48 x 16 blocks
    int lid = id - 8192;
    in = Wqkv; out = Wt_qkv; R = C_; Ccols = N3_;
    c0 = (lid % 48) * 64; r0 = (lid / 48) * 64;
  } else {                               // Wproj transpose: 16 x 16 blocks
    int lid = id - 8960;
    in = Wproj; out = Wt_proj; R = C_; Ccols = C_;
    c0 = (lid & 15) * 64; r0 = (lid >> 4) * 64;
  }
#pragma unroll
  for (int it = 0; it < 16; ++it) {
    int idx = it * 256 + tid;
    int r = idx >> 6, c = idx & 63;
    tile[c][r] = f2bf(in[(size_t)(r0 + r) * Ccols + c0 + c]);
  }
  __syncthreads();
#pragma unroll
  for (int it = 0; it < 16; ++it) {
    int idx = it * 256 + tid;
    int oc = idx >> 6, orr = idx & 63;
    out[(size_t)(c0 + oc) * R + r0 + orr] = tile[oc][orr];
  }
}

// -------- V section of qkv(bf16) -> Vt[bh][d][n], key-PERMUTED ------------
__global__ __launch_bounds__(256)
void transpose_v(const u16* __restrict__ qkv, u16* __restrict__ vt) {
  __shared__ u16 tile[64][65];
  int bh = blockIdx.y, b = bh >> 4, h = bh & 15;
  int n0 = blockIdx.x * 64;
  int tid = threadIdx.x;
#pragma unroll
  for (int it = 0; it < 16; ++it) {
    int idx = it * 256 + tid;
    int n = idx >> 6, d = idx & 63;
    tile[d][n] = qkv[(size_t)(b * N_ + n0 + n) * N3_ + 2 * C_ + h * D_ + d];
  }
  __syncthreads();
#pragma unroll
  for (int it = 0; it < 16; ++it) {
    int idx = it * 256 + tid;
    int d = idx >> 6, n = idx & 63;          // n = actual key within tile
    int np = (n & 0x23) | ((n & 0x0C) << 1) | ((n & 0x10) >> 2);  // slot
    vt[(size_t)(bh * D_ + d) * N_ + n0 + np] = tile[d][n];
  }
}

// ------- QKV GEMM, L2-DIRECT: no LDS, no barriers, no vmcnt ---------------
// R10: the LDS-ring family is structurally floored (R3-R9 invariant ~100us:
// VGPR caps 16 waves/CU; grid 768 @ 2/CU = 75% fill; barrier-per-slot is
// forced by cross-wave staging). Remove the ring: each wave loads its MFMA
// fragments straight from L2 to VGPRs (identical 16x64B coalescing pattern
// to what glds16 issued) with a manual 2-stage register double-buffer.
// 128x128 tile, 4 waves (2Mx2N), per-wave 64x64 acc[4][4] (16 MFMA/step,
// RMS head-alignment kept). Grid 24x64 = 1536 blocks; ~135 VGPR -> 3
// waves/SIMD -> 3 blocks/CU -> exactly 2 full rounds, 100% fill, zero
// inter-wave coupling. Unique A+B (23MB) is L2/L3-resident; dup reads
// (A x2, B x2 per block) ~1.5GB L2 traffic @ 34.5 TB/s ~ 45us floor.
// Operand mapping identical to the LDS path -> bitwise-identical output.
__global__ __launch_bounds__(256)
void gemm_qkv_l2(const u16* __restrict__ A, const u16* __restrict__ Bt,
                 const float* __restrict__ bias, u16* __restrict__ Cout,
                 const float* __restrict__ qn, const float* __restrict__ kn) {
  const int K = C_;
  int tid = threadIdx.x;
  int wave = tid >> 6, lane = tid & 63;
  int lrow = lane & 15, lq = lane >> 4;
  int n0 = blockIdx.x * 128;
  int m0 = blockIdx.y * 128;
  int wm = wave >> 1, wn = wave & 1;

  floatx4 acc[4][4];
#pragma unroll
  for (int i = 0; i < 4; ++i)
#pragma unroll
    for (int j = 0; j < 4; ++j) acc[i][j] = (floatx4){0.f, 0.f, 0.f, 0.f};

  const u16* pa[4];
  const u16* pb[4];
#pragma unroll
  for (int i = 0; i < 4; ++i) {
    pa[i] = A  + (size_t)(m0 + wm * 64 + i * 16 + lrow) * K + lq * 8;
    pb[i] = Bt + (size_t)(n0 + wn * 64 + i * 16 + lrow) * K + lq * 8;
  }

  bf16x8 a0[4], b0[4], a1[4], b1[4];
#pragma unroll
  for (int i = 0; i < 4; ++i) {
    a0[i] = *(const bf16x8_ma*)(pa[i]);
    b0[i] = *(const bf16x8_ma*)(pb[i]);
  }

  for (int kt = 0; kt < K; kt += 64) {
    // issue next half-step's loads, then MFMA current (loads fly under MFMA)
#pragma unroll
    for (int i = 0; i < 4; ++i) {
      a1[i] = *(const bf16x8_ma*)(pa[i] + kt + 32);
      b1[i] = *(const bf16x8_ma*)(pb[i] + kt + 32);
    }
#pragma unroll
    for (int i = 0; i < 4; ++i)
#pragma unroll
      for (int j = 0; j < 4; ++j)
        acc[i][j] = __builtin_amdgcn_mfma_f32_16x16x32_bf16(a0[i], b0[j], acc[i][j], 0, 0, 0);

    if (kt + 64 < K) {
#pragma unroll
      for (int i = 0; i < 4; ++i) {
        a0[i] = *(const bf16x8_ma*)(pa[i] + kt + 64);
        b0[i] = *(const bf16x8_ma*)(pb[i] + kt + 64);
      }
    }
#pragma unroll
    for (int i = 0; i < 4; ++i)
#pragma unroll
      for (int j = 0; j < 4; ++j)
        acc[i][j] = __builtin_amdgcn_mfma_f32_16x16x32_bf16(a1[i], b1[j], acc[i][j], 0, 0, 0);
  }

  int colbase = n0 + wn * 64;
  float bv[4];
#pragma unroll
  for (int j = 0; j < 4; ++j) bv[j] = bias[colbase + j * 16 + lrow];
#pragma unroll
  for (int i = 0; i < 4; ++i)
#pragma unroll
    for (int j = 0; j < 4; ++j)
#pragma unroll
      for (int r = 0; r < 4; ++r) acc[i][j][r] += bv[j];

  int sect = colbase >> 10;            // 0=q, 1=k, 2=v (64-col groups head-aligned)
  if (sect < 2) {
    const float* wptr = (sect == 0) ? qn : kn;
    float wv[4];
#pragma unroll
    for (int j = 0; j < 4; ++j) wv[j] = wptr[j * 16 + lrow];
#pragma unroll
    for (int i = 0; i < 4; ++i)
#pragma unroll
      for (int r = 0; r < 4; ++r) {
        float ss = 0.f;
#pragma unroll
        for (int j = 0; j < 4; ++j) { float v = acc[i][j][r]; ss += v * v; }
        ss += __shfl_xor(ss, 1);
        ss += __shfl_xor(ss, 2);
        ss += __shfl_xor(ss, 4);
        ss += __shfl_xor(ss, 8);
        float rstd = rsqrtf(ss * (1.0f / 64.0f) + 1e-6f);
#pragma unroll
        for (int j = 0; j < 4; ++j) acc[i][j][r] *= rstd * wv[j];
      }
  }

#pragma unroll
  for (int i = 0; i < 4; ++i)
#pragma unroll
    for (int j = 0; j < 4; ++j)
#pragma unroll
      for (int r = 0; r < 4; ++r) {
        int row = m0 + wm * 64 + i * 16 + lq * 4 + r;
        int col = colbase + j * 16 + lrow;
        Cout[(size_t)row * N3_ + col] = f2bf(acc[i][j][r]);
      }
}

// ------- C = A[M,*lda](bf16) * Bt[N,K]^T(bf16) + bias(f32), opt RMSNorm ---
// 128x128 tile, 4 waves, BK=32, counted-vmcnt triple-buffer + XCD swizzle.
// PROJ gemm (R7-proven, byte-identical).
__global__ __launch_bounds__(256)
void gemm_bt(const u16* __restrict__ A, const u16* __restrict__ Bt,
             const float* __restrict__ bias, void* __restrict__ Cout,
             int Ncols, int lda, int do_rms, int out_fp32,
             const float* __restrict__ qn, const float* __restrict__ kn) {
  __shared__ __align__(16) u16 sA[3][8 * 512];
  __shared__ __align__(16) u16 sB[3][8 * 512];
  const int K = C_;
  int tid = threadIdx.x;
  int wave = tid >> 6, lane = tid & 63;
  int lrow = lane & 15, lq = lane >> 4;

  int nwg = gridDim.x * gridDim.y;
  int hw = blockIdx.y * gridDim.x + blockIdx.x;
  int lg = xcd_swz(hw, nwg);
  int bx = lg % gridDim.x, by = lg / gridDim.x;
  int n0 = bx * 128;
  int m0 = by * 128;
  int wm = wave >> 1, wn = wave & 1;

  floatx4 acc[4][4];
#pragma unroll
  for (int i = 0; i < 4; ++i)
#pragma unroll
    for (int j = 0; j < 4; ++j) acc[i][j] = (floatx4){0.f, 0.f, 0.f, 0.f};

  const u16* ga0 = A  + (size_t)(m0 + (2 * wave + 0) * 16 + lrow) * lda + lq * 8;
  const u16* ga1 = A  + (size_t)(m0 + (2 * wave + 1) * 16 + lrow) * lda + lq * 8;
  const u16* gb0 = Bt + (size_t)(n0 + (2 * wave + 0) * 16 + lrow) * K + lq * 8;
  const u16* gb1 = Bt + (size_t)(n0 + (2 * wave + 1) * 16 + lrow) * K + lq * 8;
  int o0 = (2 * wave + 0) * 512;
  int o1 = (2 * wave + 1) * 512;

  u16* aA = &sA[0][0]; u16* aB = &sA[1][0]; u16* aC = &sA[2][0];
  u16* bA = &sB[0][0]; u16* bB = &sB[1][0]; u16* bC = &sB[2][0];

  glds16(ga0, aA + o0); glds16(ga1, aA + o1);
  glds16(gb0, bA + o0); glds16(gb1, bA + o1);
  glds16(ga0 + 32, aB + o0); glds16(ga1 + 32, aB + o1);
  glds16(gb0 + 32, bB + o0); glds16(gb1 + 32, bB + o1);

  for (int kt = 0; kt < K; kt += 32) {
    if (kt + 32 < K) {
      asm volatile("s_waitcnt vmcnt(4)" ::: "memory");
    } else {
      asm volatile("s_waitcnt vmcnt(0)" ::: "memory");
    }
    __builtin_amdgcn_s_barrier();
    asm volatile("" ::: "memory");

    if (kt + 64 < K) {
      glds16(ga0 + kt + 64, aC + o0);
      glds16(ga1 + kt + 64, aC + o1);
      glds16(gb0 + kt + 64, bC + o0);
      glds16(gb1 + kt + 64, bC + o1);
    }

    bf16x8 af[4], bfr[4];
#pragma unroll
    for (int i = 0; i < 4; ++i)
      af[i] = *(const bf16x8_ma*)(aA + (wm * 4 + i) * 512 + lane * 8);
#pragma unroll
    for (int j = 0; j < 4; ++j)
      bfr[j] = *(const bf16x8_ma*)(bA + (wn * 4 + j) * 512 + lane * 8);
#pragma unroll
    for (int i = 0; i < 4; ++i)
#pragma unroll
      for (int j = 0; j < 4; ++j)
        acc[i][j] = __builtin_amdgcn_mfma_f32_16x16x32_bf16(af[i], bfr[j], acc[i][j], 0, 0, 0);

    u16* t;
    t = aA; aA = aB; aB = aC; aC = t;
    t = bA; bA = bB; bB = bC; bC = t;
  }

  int colbase = n0 + wn * 64;
  float bv[4];
#pragma unroll
  for (int j = 0; j < 4; ++j) bv[j] = bias[colbase + j * 16 + lrow];
#pragma unroll
  for (int i = 0; i < 4; ++i)
#pragma unroll
    for (int j = 0; j < 4; ++j)
#pragma unroll
      for (int r = 0; r < 4; ++r) acc[i][j][r] += bv[j];

  int sect = colbase >> 10;
  if (do_rms && sect < 2) {
    const float* wptr = (sect == 0) ? qn : kn;
    float wv[4];
#pragma unroll
    for (int j = 0; j < 4; ++j) wv[j] = wptr[j * 16 + lrow];
#pragma unroll
    for (int i = 0; i < 4; ++i)
#pragma unroll
      for (int r = 0; r < 4; ++r) {
        float ss = 0.f;
#pragma unroll
        for (int j = 0; j < 4; ++j) { float v = acc[i][j][r]; ss += v * v; }
        ss += __shfl_xor(ss, 1);
        ss += __shfl_xor(ss, 2);
        ss += __shfl_xor(ss, 4);
        ss += __shfl_xor(ss, 8);
        float rstd = rsqrtf(ss * (1.0f / 64.0f) + 1e-6f);
#pragma unroll
        for (int j = 0; j < 4; ++j) acc[i][j][r] *= rstd * wv[j];
      }
  }

#pragma unroll
  for (int i = 0; i < 4; ++i)
#pragma unroll
    for (int j = 0; j < 4; ++j)
#pragma unroll
      for (int r = 0; r < 4; ++r) {
        int row = m0 + wm * 64 + i * 16 + lq * 4 + r;
        int col = colbase + j * 16 + lrow;
        if (out_fp32)
          ((float*)Cout)[(size_t)row * Ncols + col] = acc[i][j][r];
        else
          ((u16*)Cout)[(size_t)row * Ncols + col] = f2bf(acc[i][j][r]);
      }
}

// ---------------- flash attention, TRANSPOSED products --------------------
// R9 (kept, byte-identical): Q-block 256, 8 waves, same per-wave tile;
// 2 glds16/wave/tile; exp2 with cc pre-folded; mfma(ones) denom; dbuf K/V;
// setprio; T1 XCD swizzle. Measured 102 -> <100 (dropped from top-5).
__global__ __launch_bounds__(512)
void flash_attn(u16* __restrict__ qkv, const u16* __restrict__ vt) {
  __shared__ __align__(16) u16 sK[2][8 * 512];
  __shared__ __align__(16) u16 sV[2][8 * 512];
  int tid = threadIdx.x;
  int wave = tid >> 6, lane = tid & 63;
  int lrow = lane & 15, lq = lane >> 4;

  int hw = blockIdx.y * gridDim.x + blockIdx.x;   // nwg = 8*64 = 512
  int lg = xcd_swz(hw, 512);
  int qblk = lg & 7, bh = lg >> 3;
  int b = bh >> 4, h = bh & 15;
  int q0 = qblk * 256;
  const float cc = 0.125f * 1.44269504088896340736f;  // scale * log2(e)

  // Q fragments, PRE-SCALED by cc (B-operand: n=lrow=q, k=lq*8=d)
  bf16x8 qf[2][2];
#pragma unroll
  for (int i = 0; i < 2; ++i)
#pragma unroll
    for (int kq = 0; kq < 2; ++kq) {
      union { bf16x8 v; __bf16 e[8]; } t;
      t.v = *(const bf16x8_ma*)(qkv +
          (size_t)(b * N_ + q0 + wave * 32 + i * 16 + lrow) * N3_ +
          h * D_ + kq * 32 + lq * 8);
#pragma unroll
      for (int e = 0; e < 8; ++e) t.e[e] = (__bf16)((float)t.e[e] * cc);
      qf[i][kq] = t.v;
    }

  union { bf16x8 v; u16 e[8]; } one_;
#pragma unroll
  for (int e = 0; e < 8; ++e) one_.e[e] = 0x3F80;   // bf16 1.0
  bf16x8 onef = one_.v;

  floatx4 aco[2][4];
  floatx4 acl[2];
#pragma unroll
  for (int i = 0; i < 2; ++i) {
#pragma unroll
    for (int nd = 0; nd < 4; ++nd) aco[i][nd] = (floatx4){0.f, 0.f, 0.f, 0.f};
    acl[i] = (floatx4){0.f, 0.f, 0.f, 0.f};
  }

  // staging: wave w owns LDS block w for BOTH K and V (j=w>>1, kq=w&1)
  const u16* gk = qkv + (size_t)(b * N_ + (wave >> 1) * 16 + lrow) * N3_ +
                  C_ + h * D_ + (wave & 1) * 32 + lq * 8;
  const u16* gv = vt + (size_t)(bh * D_ + (wave >> 1) * 16 + lrow) * N_ +
                  (wave & 1) * 32 + lq * 8;

  u16* k_cur = &sK[0][0]; u16* k_nxt = &sK[1][0];
  u16* v_cur = &sV[0][0]; u16* v_nxt = &sV[1][0];

  glds16(gk, k_cur + wave * 512);
  glds16(gv, v_cur + wave * 512);
  __syncthreads();

  for (int kt = 0; kt < 32; ++kt) {
    if (kt < 31) {
      size_t key0n = (size_t)(kt + 1) * 64;
      glds16(gk + key0n * N3_, k_nxt + wave * 512);
      glds16(gv + key0n, v_nxt + wave * 512);
    }

    floatx4 accs[2][4];
    __builtin_amdgcn_s_setprio(1);
#pragma unroll
    for (int j = 0; j < 4; ++j) {
      bf16x8 kf0 = *(const bf16x8_ma*)(k_cur + (j * 2 + 0) * 512 + lane * 8);
      bf16x8 kf1 = *(const bf16x8_ma*)(k_cur + (j * 2 + 1) * 512 + lane * 8);
#pragma unroll
      for (int i = 0; i < 2; ++i) {
        floatx4 s = (floatx4){0.f, 0.f, 0.f, 0.f};
        s = __builtin_amdgcn_mfma_f32_16x16x32_bf16(kf0, qf[i][0], s, 0, 0, 0);
        s = __builtin_amdgcn_mfma_f32_16x16x32_bf16(kf1, qf[i][1], s, 0, 0, 0);
        accs[i][j] = s;
      }
    }
    __builtin_amdgcn_s_setprio(0);

    bf16x8 pf[2][2];
#pragma unroll
    for (int i = 0; i < 2; ++i) {
      union { bf16x8 v; __bf16 e[8]; } pk0, pk1;
#pragma unroll
      for (int j = 0; j < 4; ++j)
#pragma unroll
        for (int r = 0; r < 4; ++r) {
          float p = fexp2(accs[i][j][r]);
          if (j < 2) pk0.e[(j & 1) * 4 + r] = (__bf16)p;
          else       pk1.e[(j & 1) * 4 + r] = (__bf16)p;
        }
      pf[i][0] = pk0.v;
      pf[i][1] = pk1.v;
    }

    __builtin_amdgcn_s_setprio(1);
#pragma unroll
    for (int kq = 0; kq < 2; ++kq) {
#pragma unroll
      for (int nd = 0; nd < 4; ++nd) {
        bf16x8 vf = *(const bf16x8_ma*)(v_cur + (nd * 2 + kq) * 512 + lane * 8);
        aco[0][nd] = __builtin_amdgcn_mfma_f32_16x16x32_bf16(vf, pf[0][kq], aco[0][nd], 0, 0, 0);
        aco[1][nd] = __builtin_amdgcn_mfma_f32_16x16x32_bf16(vf, pf[1][kq], aco[1][nd], 0, 0, 0);
      }
      acl[0] = __builtin_amdgcn_mfma_f32_16x16x32_bf16(onef, pf[0][kq], acl[0], 0, 0, 0);
      acl[1] = __builtin_amdgcn_mfma_f32_16x16x32_bf16(onef, pf[1][kq], acl[1], 0, 0, 0);
    }
    __builtin_amdgcn_s_setprio(0);

    __syncthreads();
    u16* t0 = k_cur; k_cur = k_nxt; k_nxt = t0;
    u16* t1 = v_cur; v_cur = v_nxt; v_nxt = t1;
  }

#pragma unroll
  for (int i = 0; i < 2; ++i) {
    float inv = 1.0f / acl[i][0];
    int row = q0 + wave * 32 + i * 16 + lrow;
#pragma unroll
    for (int nd = 0; nd < 4; ++nd) {
      union { u16 a[4]; uint2 u; } st;
#pragma unroll
      for (int r = 0; r < 4; ++r) st.a[r] = f2bf(aco[i][nd][r] * inv);
      *(uint2*)(qkv + (size_t)(b * N_ + row) * N3_ + h * D_ + nd * 16 + lq * 4) = st.u;
    }
  }
}

extern "C" void kernel_launch(void* const* d_in, const int* in_sizes, int n_in,
                              void* d_out, int out_size, void* d_ws, size_t ws_size,
                              hipStream_t stream) {
  (void)in_sizes; (void)n_in; (void)out_size; (void)ws_size;
  const float* x     = (const float*)d_in[0];
  const float* Wqkv  = (const float*)d_in[1];
  const float* bqkv  = (const float*)d_in[2];
  const float* Wproj = (const float*)d_in[3];
  const float* bproj = (const float*)d_in[4];
  const float* qn    = (const float*)d_in[5];
  const float* kn    = (const float*)d_in[6];
  float* out = (float*)d_out;

  char* ws = (char*)d_ws;
  u16* xb      = (u16*)ws;  ws += (size_t)M_ * C_ * 2;            // 16.8 MB
  u16* Wt_qkv  = (u16*)ws;  ws += (size_t)N3_ * C_ * 2;           // 6.3 MB
  u16* Wt_proj = (u16*)ws;  ws += (size_t)C_ * C_ * 2;            // 2.1 MB
  u16* qkv     = (u16*)ws;  ws += (size_t)M_ * N3_ * 2;           // 50.3 MB
  u16* vt      = (u16*)ws;  ws += (size_t)B_ * H_ * D_ * N_ * 2;  // 16.8 MB

  prep<<<dim3(8192 + 768 + 256), 256, 0, stream>>>(
      (const float4*)x, (uint2*)xb, Wqkv, Wt_qkv, Wproj, Wt_proj);
  gemm_qkv_l2<<<dim3(N3_ / 128, M_ / 128), 256, 0, stream>>>(
      xb, Wt_qkv, bqkv, qkv, qn, kn);
  transpose_v<<<dim3(N_ / 64, B_ * H_), 256, 0, stream>>>(qkv, vt);
  flash_attn<<<dim3(N_ / 256, B_ * H_), 512, 0, stream>>>(qkv, vt);
  gemm_bt<<<dim3(C_ / 128, M_ / 128), 256, 0, stream>>>(
      qkv, Wt_proj, bproj, out, C_, N3_, 0, 1, qn, kn);
}

// Round 12
// 298.546 us; speedup vs baseline: 1.2976x; 1.2976x over previous
//
#include <hip/hip_runtime.h>
#include <stdint.h>

#define B_ 4
#define N_ 2048
#define C_ 1024
#define H_ 16
#define D_ 64
#define M_ (B_*N_)      // 8192 rows
#define N3_ (3*C_)      // 3072

typedef __attribute__((ext_vector_type(8))) __bf16 bf16x8;
typedef bf16x8 bf16x8_ma __attribute__((may_alias));
typedef __attribute__((ext_vector_type(4))) float floatx4;
typedef unsigned short u16;
typedef unsigned int u32;

typedef __attribute__((address_space(1))) const void void_g;
typedef __attribute__((address_space(3))) void void_l;

__device__ __forceinline__ void glds16(const void* g, void* l) {
  __builtin_amdgcn_global_load_lds((void_g*)g, (void_l*)l, 16, 0, 0);
}

__device__ __forceinline__ u16 f2bf(float f) {
  union { float f; u32 u; } x; x.f = f;
  u32 r = x.u + 0x7fffu + ((x.u >> 16) & 1u);   // RNE
  return (u16)(r >> 16);
}

__device__ __forceinline__ float fexp2(float x) {
#if __has_builtin(__builtin_amdgcn_exp2f)
  return __builtin_amdgcn_exp2f(x);
#else
  return exp2f(x);
#endif
}

// T1 swizzle: kept ONLY for flash (R6 isolated: helps flash KV locality,
// null-to-harmful FETCH on the gemm).
__device__ __forceinline__ int xcd_swz(int hw, int nwg) {
  int per = nwg >> 3;
  return (hw & 7) * per + (hw >> 3);
}

// ---------------- fused prep: x->bf16 + both weight transposes -----------
// R10 (kept): 3 dispatches -> 1, measured ~ -7us via R10 arithmetic.
__global__ __launch_bounds__(256)
void prep(const float4* __restrict__ x4, uint2* __restrict__ xb,
          const float* __restrict__ Wqkv, u16* __restrict__ Wt_qkv,
          const float* __restrict__ Wproj, u16* __restrict__ Wt_proj) {
  __shared__ u16 tile[64][65];
  int id = blockIdx.x;
  int tid = threadIdx.x;

  if (id < 8192) {                       // convert_x: 8192*256 == M_*C_/4
    int idx = id * 256 + tid;
    float4 v = x4[idx];
    union { u16 a[4]; uint2 u; } p;
    p.a[0] = f2bf(v.x); p.a[1] = f2bf(v.y); p.a[2] = f2bf(v.z); p.a[3] = f2bf(v.w);
    xb[idx] = p.u;
    return;
  }

  const float* in; u16* out; int R, Ccols, c0, r0;
  if (id < 8192 + 768) {                 // Wqkv transpose: 48 x 16 blocks
    int lid = id - 8192;
    in = Wqkv; out = Wt_qkv; R = C_; Ccols = N3_;
    c0 = (lid % 48) * 64; r0 = (lid / 48) * 64;
  } else {                               // Wproj transpose: 16 x 16 blocks
    int lid = id - 8960;
    in = Wproj; out = Wt_proj; R = C_; Ccols = C_;
    c0 = (lid & 15) * 64; r0 = (lid >> 4) * 64;
  }
#pragma unroll
  for (int it = 0; it < 16; ++it) {
    int idx = it * 256 + tid;
    int r = idx >> 6, c = idx & 63;
    tile[c][r] = f2bf(in[(size_t)(r0 + r) * Ccols + c0 + c]);
  }
  __syncthreads();
#pragma unroll
  for (int it = 0; it < 16; ++it) {
    int idx = it * 256 + tid;
    int oc = idx >> 6, orr = idx & 63;
    out[(size_t)(c0 + oc) * R + r0 + orr] = tile[oc][orr];
  }
}

// -------- V section of qkv(bf16) -> Vt[bh][d][n], key-PERMUTED ------------
__global__ __launch_bounds__(256)
void transpose_v(const u16* __restrict__ qkv, u16* __restrict__ vt) {
  __shared__ u16 tile[64][65];
  int bh = blockIdx.y, b = bh >> 4, h = bh & 15;
  int n0 = blockIdx.x * 64;
  int tid = threadIdx.x;
#pragma unroll
  for (int it = 0; it < 16; ++it) {
    int idx = it * 256 + tid;
    int n = idx >> 6, d = idx & 63;
    tile[d][n] = qkv[(size_t)(b * N_ + n0 + n) * N3_ + 2 * C_ + h * D_ + d];
  }
  __syncthreads();
#pragma unroll
  for (int it = 0; it < 16; ++it) {
    int idx = it * 256 + tid;
    int d = idx >> 6, n = idx & 63;          // n = actual key within tile
    int np = (n & 0x23) | ((n & 0x0C) << 1) | ((n & 0x10) >> 2);  // slot
    vt[(size_t)(bh * D_ + d) * N_ + n0 + np] = tile[d][n];
  }
}

// ------- QKV GEMM: 128(M)x256(N) tile, 8 waves, counted-vmcnt ring --------
// R11: REVERTED to the R7-proven config (measured ~100us). R10's L2-direct
// variant (no LDS, reg-dbuf) hit 194us: per-wave vmcnt waits serialize on
// L2 latency; glds16's deep DMA queue + barrier-decoupled consumer is the
// better latency amortizer. The no-LDS branch is closed.
__global__ __launch_bounds__(512)
void gemm_qkv(const u16* __restrict__ A, const u16* __restrict__ Bt,
              const float* __restrict__ bias, u16* __restrict__ Cout,
              const float* __restrict__ qn, const float* __restrict__ kn) {
  __shared__ __align__(16) u16 sA[3][8 * 512];    // 3 x 8KB
  __shared__ __align__(16) u16 sB[3][16 * 512];   // 3 x 16KB
  const int K = C_;
  int tid = threadIdx.x;
  int wave = tid >> 6, lane = tid & 63;
  int lrow = lane & 15, lq = lane >> 4;
  int n0 = blockIdx.x * 256;
  int m0 = blockIdx.y * 128;
  int wm = wave >> 2, wn = wave & 3;

  floatx4 acc[4][4];
#pragma unroll
  for (int i = 0; i < 4; ++i)
#pragma unroll
    for (int j = 0; j < 4; ++j) acc[i][j] = (floatx4){0.f, 0.f, 0.f, 0.f};

  const u16* ga  = A  + (size_t)(m0 + wave * 16 + lrow) * K + lq * 8;
  const u16* gb0 = Bt + (size_t)(n0 + (2 * wave + 0) * 16 + lrow) * K + lq * 8;
  const u16* gb1 = Bt + (size_t)(n0 + (2 * wave + 1) * 16 + lrow) * K + lq * 8;
  int oa  = wave * 512;
  int ob0 = (2 * wave + 0) * 512;
  int ob1 = (2 * wave + 1) * 512;

#define STAGE(kt_, s_)                      \
  do {                                      \
    glds16(ga  + (kt_), &sA[s_][oa]);       \
    glds16(gb0 + (kt_), &sB[s_][ob0]);      \
    glds16(gb1 + (kt_), &sB[s_][ob1]);      \
  } while (0)

  STAGE(0, 0);
  STAGE(32, 1);

  int slot = 0;
  for (int kt = 0; kt < K; kt += 32) {
    if (kt + 32 < K) {
      asm volatile("s_waitcnt vmcnt(3)" ::: "memory");
    } else {
      asm volatile("s_waitcnt vmcnt(0)" ::: "memory");
    }
    __builtin_amdgcn_s_barrier();
    asm volatile("" ::: "memory");

    if (kt + 64 < K) {
      int s2 = slot + 2; if (s2 >= 3) s2 -= 3;
      STAGE(kt + 64, s2);
    }

    bf16x8 af[4], bfr[4];
#pragma unroll
    for (int i = 0; i < 4; ++i)
      af[i] = *(const bf16x8_ma*)(&sA[slot][(wm * 4 + i) * 512 + lane * 8]);
#pragma unroll
    for (int j = 0; j < 4; ++j)
      bfr[j] = *(const bf16x8_ma*)(&sB[slot][(wn * 4 + j) * 512 + lane * 8]);
#pragma unroll
    for (int i = 0; i < 4; ++i)
#pragma unroll
      for (int j = 0; j < 4; ++j)
        acc[i][j] = __builtin_amdgcn_mfma_f32_16x16x32_bf16(af[i], bfr[j], acc[i][j], 0, 0, 0);

    ++slot; if (slot >= 3) slot = 0;
  }
#undef STAGE

  int colbase = n0 + wn * 64;
  float bv[4];
#pragma unroll
  for (int j = 0; j < 4; ++j) bv[j] = bias[colbase + j * 16 + lrow];
#pragma unroll
  for (int i = 0; i < 4; ++i)
#pragma unroll
    for (int j = 0; j < 4; ++j)
#pragma unroll
      for (int r = 0; r < 4; ++r) acc[i][j][r] += bv[j];

  int sect = colbase >> 10;            // 0=q, 1=k, 2=v
  if (sect < 2) {
    const float* wptr = (sect == 0) ? qn : kn;
    float wv[4];
#pragma unroll
    for (int j = 0; j < 4; ++j) wv[j] = wptr[j * 16 + lrow];
#pragma unroll
    for (int i = 0; i < 4; ++i)
#pragma unroll
      for (int r = 0; r < 4; ++r) {
        float ss = 0.f;
#pragma unroll
        for (int j = 0; j < 4; ++j) { float v = acc[i][j][r]; ss += v * v; }
        ss += __shfl_xor(ss, 1);
        ss += __shfl_xor(ss, 2);
        ss += __shfl_xor(ss, 4);
        ss += __shfl_xor(ss, 8);
        float rstd = rsqrtf(ss * (1.0f / 64.0f) + 1e-6f);
#pragma unroll
        for (int j = 0; j < 4; ++j) acc[i][j][r] *= rstd * wv[j];
      }
  }

#pragma unroll
  for (int i = 0; i < 4; ++i)
#pragma unroll
    for (int j = 0; j < 4; ++j)
#pragma unroll
      for (int r = 0; r < 4; ++r) {
        int row = m0 + wm * 64 + i * 16 + lq * 4 + r;
        int col = colbase + j * 16 + lrow;
        Cout[(size_t)row * N3_ + col] = f2bf(acc[i][j][r]);
      }
}

// ------- C = A[M,*lda](bf16) * Bt[N,K]^T(bf16) + bias(f32), opt RMSNorm ---
// 128x128 tile, 4 waves, BK=32, counted-vmcnt triple-buffer + XCD swizzle.
// PROJ gemm (R7-proven, byte-identical).
__global__ __launch_bounds__(256)
void gemm_bt(const u16* __restrict__ A, const u16* __restrict__ Bt,
             const float* __restrict__ bias, void* __restrict__ Cout,
             int Ncols, int lda, int do_rms, int out_fp32,
             const float* __restrict__ qn, const float* __restrict__ kn) {
  __shared__ __align__(16) u16 sA[3][8 * 512];
  __shared__ __align__(16) u16 sB[3][8 * 512];
  const int K = C_;
  int tid = threadIdx.x;
  int wave = tid >> 6, lane = tid & 63;
  int lrow = lane & 15, lq = lane >> 4;

  int nwg = gridDim.x * gridDim.y;
  int hw = blockIdx.y * gridDim.x + blockIdx.x;
  int lg = xcd_swz(hw, nwg);
  int bx = lg % gridDim.x, by = lg / gridDim.x;
  int n0 = bx * 128;
  int m0 = by * 128;
  int wm = wave >> 1, wn = wave & 1;

  floatx4 acc[4][4];
#pragma unroll
  for (int i = 0; i < 4; ++i)
#pragma unroll
    for (int j = 0; j < 4; ++j) acc[i][j] = (floatx4){0.f, 0.f, 0.f, 0.f};

  const u16* ga0 = A  + (size_t)(m0 + (2 * wave + 0) * 16 + lrow) * lda + lq * 8;
  const u16* ga1 = A  + (size_t)(m0 + (2 * wave + 1) * 16 + lrow) * lda + lq * 8;
  const u16* gb0 = Bt + (size_t)(n0 + (2 * wave + 0) * 16 + lrow) * K + lq * 8;
  const u16* gb1 = Bt + (size_t)(n0 + (2 * wave + 1) * 16 + lrow) * K + lq * 8;
  int o0 = (2 * wave + 0) * 512;
  int o1 = (2 * wave + 1) * 512;

  u16* aA = &sA[0][0]; u16* aB = &sA[1][0]; u16* aC = &sA[2][0];
  u16* bA = &sB[0][0]; u16* bB = &sB[1][0]; u16* bC = &sB[2][0];

  glds16(ga0, aA + o0); glds16(ga1, aA + o1);
  glds16(gb0, bA + o0); glds16(gb1, bA + o1);
  glds16(ga0 + 32, aB + o0); glds16(ga1 + 32, aB + o1);
  glds16(gb0 + 32, bB + o0); glds16(gb1 + 32, bB + o1);

  for (int kt = 0; kt < K; kt += 32) {
    if (kt + 32 < K) {
      asm volatile("s_waitcnt vmcnt(4)" ::: "memory");
    } else {
      asm volatile("s_waitcnt vmcnt(0)" ::: "memory");
    }
    __builtin_amdgcn_s_barrier();
    asm volatile("" ::: "memory");

    if (kt + 64 < K) {
      glds16(ga0 + kt + 64, aC + o0);
      glds16(ga1 + kt + 64, aC + o1);
      glds16(gb0 + kt + 64, bC + o0);
      glds16(gb1 + kt + 64, bC + o1);
    }

    bf16x8 af[4], bfr[4];
#pragma unroll
    for (int i = 0; i < 4; ++i)
      af[i] = *(const bf16x8_ma*)(aA + (wm * 4 + i) * 512 + lane * 8);
#pragma unroll
    for (int j = 0; j < 4; ++j)
      bfr[j] = *(const bf16x8_ma*)(bA + (wn * 4 + j) * 512 + lane * 8);
#pragma unroll
    for (int i = 0; i < 4; ++i)
#pragma unroll
      for (int j = 0; j < 4; ++j)
        acc[i][j] = __builtin_amdgcn_mfma_f32_16x16x32_bf16(af[i], bfr[j], acc[i][j], 0, 0, 0);

    u16* t;
    t = aA; aA = aB; aB = aC; aC = t;
    t = bA; bA = bB; bB = bC; bC = t;
  }

  int colbase = n0 + wn * 64;
  float bv[4];
#pragma unroll
  for (int j = 0; j < 4; ++j) bv[j] = bias[colbase + j * 16 + lrow];
#pragma unroll
  for (int i = 0; i < 4; ++i)
#pragma unroll
    for (int j = 0; j < 4; ++j)
#pragma unroll
      for (int r = 0; r < 4; ++r) acc[i][j][r] += bv[j];

  int sect = colbase >> 10;
  if (do_rms && sect < 2) {
    const float* wptr = (sect == 0) ? qn : kn;
    float wv[4];
#pragma unroll
    for (int j = 0; j < 4; ++j) wv[j] = wptr[j * 16 + lrow];
#pragma unroll
    for (int i = 0; i < 4; ++i)
#pragma unroll
      for (int r = 0; r < 4; ++r) {
        float ss = 0.f;
#pragma unroll
        for (int j = 0; j < 4; ++j) { float v = acc[i][j][r]; ss += v * v; }
        ss += __shfl_xor(ss, 1);
        ss += __shfl_xor(ss, 2);
        ss += __shfl_xor(ss, 4);
        ss += __shfl_xor(ss, 8);
        float rstd = rsqrtf(ss * (1.0f / 64.0f) + 1e-6f);
#pragma unroll
        for (int j = 0; j < 4; ++j) acc[i][j][r] *= rstd * wv[j];
      }
  }

#pragma unroll
  for (int i = 0; i < 4; ++i)
#pragma unroll
    for (int j = 0; j < 4; ++j)
#pragma unroll
      for (int r = 0; r < 4; ++r) {
        int row = m0 + wm * 64 + i * 16 + lq * 4 + r;
        int col = colbase + j * 16 + lrow;
        if (out_fp32)
          ((float*)Cout)[(size_t)row * Ncols + col] = acc[i][j][r];
        else
          ((u16*)Cout)[(size_t)row * Ncols + col] = f2bf(acc[i][j][r]);
      }
}

// ---------------- flash attention, TRANSPOSED products --------------------
// R9 (kept, byte-identical): Q-block 256, 8 waves, same per-wave tile;
// 2 glds16/wave/tile; exp2 with cc pre-folded; mfma(ones) denom; dbuf K/V;
// setprio; T1 XCD swizzle.
__global__ __launch_bounds__(512)
void flash_attn(u16* __restrict__ qkv, const u16* __restrict__ vt) {
  __shared__ __align__(16) u16 sK[2][8 * 512];
  __shared__ __align__(16) u16 sV[2][8 * 512];
  int tid = threadIdx.x;
  int wave = tid >> 6, lane = tid & 63;
  int lrow = lane & 15, lq = lane >> 4;

  int hw = blockIdx.y * gridDim.x + blockIdx.x;   // nwg = 8*64 = 512
  int lg = xcd_swz(hw, 512);
  int qblk = lg & 7, bh = lg >> 3;
  int b = bh >> 4, h = bh & 15;
  int q0 = qblk * 256;
  const float cc = 0.125f * 1.44269504088896340736f;  // scale * log2(e)

  // Q fragments, PRE-SCALED by cc (B-operand: n=lrow=q, k=lq*8=d)
  bf16x8 qf[2][2];
#pragma unroll
  for (int i = 0; i < 2; ++i)
#pragma unroll
    for (int kq = 0; kq < 2; ++kq) {
      union { bf16x8 v; __bf16 e[8]; } t;
      t.v = *(const bf16x8_ma*)(qkv +
          (size_t)(b * N_ + q0 + wave * 32 + i * 16 + lrow) * N3_ +
          h * D_ + kq * 32 + lq * 8);
#pragma unroll
      for (int e = 0; e < 8; ++e) t.e[e] = (__bf16)((float)t.e[e] * cc);
      qf[i][kq] = t.v;
    }

  union { bf16x8 v; u16 e[8]; } one_;
#pragma unroll
  for (int e = 0; e < 8; ++e) one_.e[e] = 0x3F80;   // bf16 1.0
  bf16x8 onef = one_.v;

  floatx4 aco[2][4];
  floatx4 acl[2];
#pragma unroll
  for (int i = 0; i < 2; ++i) {
#pragma unroll
    for (int nd = 0; nd < 4; ++nd) aco[i][nd] = (floatx4){0.f, 0.f, 0.f, 0.f};
    acl[i] = (floatx4){0.f, 0.f, 0.f, 0.f};
  }

  // staging: wave w owns LDS block w for BOTH K and V (j=w>>1, kq=w&1)
  const u16* gk = qkv + (size_t)(b * N_ + (wave >> 1) * 16 + lrow) * N3_ +
                  C_ + h * D_ + (wave & 1) * 32 + lq * 8;
  const u16* gv = vt + (size_t)(bh * D_ + (wave >> 1) * 16 + lrow) * N_ +
                  (wave & 1) * 32 + lq * 8;

  u16* k_cur = &sK[0][0]; u16* k_nxt = &sK[1][0];
  u16* v_cur = &sV[0][0]; u16* v_nxt = &sV[1][0];

  glds16(gk, k_cur + wave * 512);
  glds16(gv, v_cur + wave * 512);
  __syncthreads();

  for (int kt = 0; kt < 32; ++kt) {
    if (kt < 31) {
      size_t key0n = (size_t)(kt + 1) * 64;
      glds16(gk + key0n * N3_, k_nxt + wave * 512);
      glds16(gv + key0n, v_nxt + wave * 512);
    }

    floatx4 accs[2][4];
    __builtin_amdgcn_s_setprio(1);
#pragma unroll
    for (int j = 0; j < 4; ++j) {
      bf16x8 kf0 = *(const bf16x8_ma*)(k_cur + (j * 2 + 0) * 512 + lane * 8);
      bf16x8 kf1 = *(const bf16x8_ma*)(k_cur + (j * 2 + 1) * 512 + lane * 8);
#pragma unroll
      for (int i = 0; i < 2; ++i) {
        floatx4 s = (floatx4){0.f, 0.f, 0.f, 0.f};
        s = __builtin_amdgcn_mfma_f32_16x16x32_bf16(kf0, qf[i][0], s, 0, 0, 0);
        s = __builtin_amdgcn_mfma_f32_16x16x32_bf16(kf1, qf[i][1], s, 0, 0, 0);
        accs[i][j] = s;
      }
    }
    __builtin_amdgcn_s_setprio(0);

    bf16x8 pf[2][2];
#pragma unroll
    for (int i = 0; i < 2; ++i) {
      union { bf16x8 v; __bf16 e[8]; } pk0, pk1;
#pragma unroll
      for (int j = 0; j < 4; ++j)
#pragma unroll
        for (int r = 0; r < 4; ++r) {
          float p = fexp2(accs[i][j][r]);
          if (j < 2) pk0.e[(j & 1) * 4 + r] = (__bf16)p;
          else       pk1.e[(j & 1) * 4 + r] = (__bf16)p;
        }
      pf[i][0] = pk0.v;
      pf[i][1] = pk1.v;
    }

    __builtin_amdgcn_s_setprio(1);
#pragma unroll
    for (int kq = 0; kq < 2; ++kq) {
#pragma unroll
      for (int nd = 0; nd < 4; ++nd) {
        bf16x8 vf = *(const bf16x8_ma*)(v_cur + (nd * 2 + kq) * 512 + lane * 8);
        aco[0][nd] = __builtin_amdgcn_mfma_f32_16x16x32_bf16(vf, pf[0][kq], aco[0][nd], 0, 0, 0);
        aco[1][nd] = __builtin_amdgcn_mfma_f32_16x16x32_bf16(vf, pf[1][kq], aco[1][nd], 0, 0, 0);
      }
      acl[0] = __builtin_amdgcn_mfma_f32_16x16x32_bf16(onef, pf[0][kq], acl[0], 0, 0, 0);
      acl[1] = __builtin_amdgcn_mfma_f32_16x16x32_bf16(onef, pf[1][kq], acl[1], 0, 0, 0);
    }
    __builtin_amdgcn_s_setprio(0);

    __syncthreads();
    u16* t0 = k_cur; k_cur = k_nxt; k_nxt = t0;
    u16* t1 = v_cur; v_cur = v_nxt; v_nxt = t1;
  }

#pragma unroll
  for (int i = 0; i < 2; ++i) {
    float inv = 1.0f / acl[i][0];
    int row = q0 + wave * 32 + i * 16 + lrow;
#pragma unroll
    for (int nd = 0; nd < 4; ++nd) {
      union { u16 a[4]; uint2 u; } st;
#pragma unroll
      for (int r = 0; r < 4; ++r) st.a[r] = f2bf(aco[i][nd][r] * inv);
      *(uint2*)(qkv + (size_t)(b * N_ + row) * N3_ + h * D_ + nd * 16 + lq * 4) = st.u;
    }
  }
}

extern "C" void kernel_launch(void* const* d_in, const int* in_sizes, int n_in,
                              void* d_out, int out_size, void* d_ws, size_t ws_size,
                              hipStream_t stream) {
  (void)in_sizes; (void)n_in; (void)out_size; (void)ws_size;
  const float* x     = (const float*)d_in[0];
  const float* Wqkv  = (const float*)d_in[1];
  const float* bqkv  = (const float*)d_in[2];
  const float* Wproj = (const float*)d_in[3];
  const float* bproj = (const float*)d_in[4];
  const float* qn    = (const float*)d_in[5];
  const float* kn    = (const float*)d_in[6];
  float* out = (float*)d_out;

  char* ws = (char*)d_ws;
  u16* xb      = (u16*)ws;  ws += (size_t)M_ * C_ * 2;            // 16.8 MB
  u16* Wt_qkv  = (u16*)ws;  ws += (size_t)N3_ * C_ * 2;           // 6.3 MB
  u16* Wt_proj = (u16*)ws;  ws += (size_t)C_ * C_ * 2;            // 2.1 MB
  u16* qkv     = (u16*)ws;  ws += (size_t)M_ * N3_ * 2;           // 50.3 MB
  u16* vt      = (u16*)ws;  ws += (size_t)B_ * H_ * D_ * N_ * 2;  // 16.8 MB

  prep<<<dim3(8192 + 768 + 256), 256, 0, stream>>>(
      (const float4*)x, (uint2*)xb, Wqkv, Wt_qkv, Wproj, Wt_proj);
  gemm_qkv<<<dim3(N3_ / 256, M_ / 128), 512, 0, stream>>>(
      xb, Wt_qkv, bqkv, qkv, qn, kn);
  transpose_v<<<dim3(N_ / 64, B_ * H_), 256, 0, stream>>>(qkv, vt);
  flash_attn<<<dim3(N_ / 256, B_ * H_), 512, 0, stream>>>(qkv, vt);
  gemm_bt<<<dim3(C_ / 128, M_ / 128), 256, 0, stream>>>(
      qkv, Wt_proj, bproj, out, C_, N3_, 0, 1, qn, kn);
}